// Round 16
// baseline (174.212 us; speedup 1.0000x reference)
//
#include <hip/hip_runtime.h>
#include <math.h>

// Problem constants (fixed by the reference)
#define N_TOT 200000
#define D_    32
#define MK    1024          // M*K = 64*16
#define EPS_DIV  1e-29f

// Decomposition: BLOCK = 16-row strip x FULL 1024-col row; 8 waves own 8
// adjacent 128-col slices; cooperative row-linear store writes each output
// row as ONE dense 4 KB burst (4 waves x 1 KB simultaneously).
#define ROWS   16
#define NT     8            // 16-col MFMA tiles per wave (128 cols)
#define NSTRIP (N_TOT / ROWS)        // 12500 strips = tasks
#define NBLK   2048         // 2 blk/CU resident (64 KB LDS), ~6.1 iters/block
#define LDSF   1024         // stage row stride in f32 (no pad; XOR swizzle)

typedef __attribute__((ext_vector_type(8))) short short8;
typedef __attribute__((ext_vector_type(4))) float f32x4;

__device__ __forceinline__ unsigned short f2bf(float x) {
    unsigned int u = __float_as_uint(x);
    u += 0x7FFFu + ((u >> 16) & 1u);          // round-to-nearest-even
    return (unsigned short)(u >> 16);
}
__device__ __forceinline__ float bf2f(unsigned short h) {
    return __uint_as_float(((unsigned int)h) << 16);
}

// ---------------------------------------------------------------------------
// Prep: softmax(alpha) folded with affine epilogue, split into bf16 hi/lo.
//   W[mk][d] = softmax(alpha[mk])[d] / (pos-neg+eps)   -> Whi + Wlo (bf16)
//   off[mk]  = (-th-neg)/(pos-neg+eps)
// Then B = clip( T·W + off, 0, 1 ).  (|temp|<1e-5 zeroing folded away:
// <= ~5e-5 output delta, validated R7/R8/R10/R11 — absmax at 0.0039 floor.)
// ---------------------------------------------------------------------------
__global__ __launch_bounds__(256) void prep_kernel(
    const float* __restrict__ alpha, const float* __restrict__ th,
    const float* __restrict__ amb,
    unsigned short* __restrict__ Whi, unsigned short* __restrict__ Wlo,
    float* __restrict__ off)
{
    int mk = blockIdx.x * 256 + threadIdx.x;
    if (mk >= MK) return;
    float v[D_];
    float mx = -1e30f;
#pragma unroll
    for (int d = 0; d < D_; ++d) { v[d] = alpha[mk * D_ + d]; mx = fmaxf(mx, v[d]); }
    float sum = 0.f;
#pragma unroll
    for (int d = 0; d < D_; ++d) { v[d] = expf(v[d] - mx); sum += v[d]; }
    float pos = amb[mk * 2 + 0];
    float neg = amb[mk * 2 + 1];
    float s  = 1.0f / (pos - neg + EPS_DIV);
    float si = s / sum;
#pragma unroll
    for (int d = 0; d < D_; ++d) {
        float w = v[d] * si;
        unsigned short h = f2bf(w);
        Whi[mk * D_ + d] = h;
        Wlo[mk * D_ + d] = f2bf(w - bf2f(h));
    }
    off[mk] = (0.0f - th[mk] - neg) * s;
}

// ---------------------------------------------------------------------------
// Main: FULL-ROW block-cooperative strip kernel (contiguity axis, final rung).
// 512 threads = 8 waves; wave wid owns cols wid*128..+127 (swapped-operand
// MFMA, R8/R10-verified mapping: lane's f32x4 = 4 consecutive mk of one
// n-row -> one ds_write_b128 into stage[16][1024], XOR-swizzled 16B chunks).
// Store phase (all 512 threads): 8 steps x {ds_read_b128, epilogue,
// global_store_dwordx4}; each step writes rows 2s,2s+1 — every 4 KB output
// row is one dense burst from 4 waves of ONE block at ONE instant (R11 split
// each row across 2 blocks at uncorrelated times). T strip now read by one
// block (halves T HBM traffic).
// 3-MFMA hi/lo split keeps fp32-level accuracy (Tlo*Wlo term dropped).
// ---------------------------------------------------------------------------
__global__ __launch_bounds__(512, 4) void fern_mfma(
    const float* __restrict__ T,
    const unsigned short* __restrict__ Whi, const unsigned short* __restrict__ Wlo,
    const float* __restrict__ off, float* __restrict__ out)
{
    __shared__ float stage[ROWS][LDSF];         // 64 KB -> 2 blocks/CU

    const int tid  = threadIdx.x;
    const int lane = tid & 63;
    const int wid  = tid >> 6;                  // 0..7
    const int lc   = lane & 15;                 // A row (mk) / B col (n)
    const int lk   = lane >> 4;                 // k-group (8 contiguous k)
    const int mk0  = wid * 128;                 // this wave's 128-col slice

    // ---- hoist W fragments (A operand, swapped) for this wave's 128 cols
    short8 wh[NT], wl[NT];
#pragma unroll
    for (int t = 0; t < NT; ++t) {
        long c = (long)(mk0 + t * 16 + lc);
        wh[t] = *(const short8*)(Whi + c * D_ + lk * 8);
        wl[t] = *(const short8*)(Wlo + c * D_ + lk * 8);
    }
    // ---- store-phase constants: thread covers cols 4*sc .. +3
    const int sc  = tid & 255;                  // 16B chunk within full row
    const int sr0 = tid >> 8;                   // row parity (0/1)
    const f32x4 ofv = *(const f32x4*)(off + 4 * sc);

    // ---- grid-stride over strips
    for (int task = blockIdx.x; task < NSTRIP; task += NBLK) {
        const int n0 = task * ROWS;

        // T fragment (B operand): col n = n0+lc, k = lk*8 .. +7  (32 B of f32)
        const float* tp = T + (long)(n0 + lc) * D_ + lk * 8;
        float4 v0 = *(const float4*)tp;
        float4 v1 = *(const float4*)(tp + 4);
        float xs[8] = { v0.x, v0.y, v0.z, v0.w, v1.x, v1.y, v1.z, v1.w };
        short8 ah, al;
#pragma unroll
        for (int j = 0; j < 8; ++j) {
            unsigned short h = f2bf(xs[j]);
            ah[j] = (short)h;
            al[j] = (short)f2bf(xs[j] - bf2f(h));
        }

        // ---- compute 8 tiles; stage raw acc (1 ds_write_b128 per tile)
        // D[mk][n] swapped: n-row = lc, mk chunk = wid*32 + t*4 + lk
#pragma unroll
        for (int t = 0; t < NT; ++t) {
            f32x4 acc = { 0.f, 0.f, 0.f, 0.f };
            acc = __builtin_amdgcn_mfma_f32_16x16x32_bf16(wh[t], ah, acc, 0, 0, 0);
            acc = __builtin_amdgcn_mfma_f32_16x16x32_bf16(wh[t], al, acc, 0, 0, 0);
            acc = __builtin_amdgcn_mfma_f32_16x16x32_bf16(wl[t], ah, acc, 0, 0, 0);
            const int chunk = (wid * 32 + t * 4 + lk) ^ (lc & 7);   // XOR swizzle
            *(f32x4*)&stage[lc][chunk * 4] = acc;
        }
        __syncthreads();

        // ---- cooperative row-linear store: step s covers rows 2s, 2s+1;
        // each wave-instruction = 1024 B contiguous; each ROW = one dense
        // 4 KB burst from 4 waves simultaneously.
#pragma unroll
        for (int s = 0; s < 8; ++s) {
            const int r = 2 * s + sr0;
            const int k = sc ^ (r & 7);                              // un-swizzle
            f32x4 v = *(const f32x4*)&stage[r][k * 4];
            f32x4 rr;
#pragma unroll
            for (int j = 0; j < 4; ++j)
                rr[j] = fminf(fmaxf(v[j] + ofv[j], 0.f), 1.f);
            *(f32x4*)(out + (long)(n0 + r) * MK + 4 * sc) = rr;
        }
        __syncthreads();
    }
}

extern "C" void kernel_launch(void* const* d_in, const int* in_sizes, int n_in,
                              void* d_out, int out_size, void* d_ws, size_t ws_size,
                              hipStream_t stream)
{
    const float* T     = (const float*)d_in[0];
    const float* alpha = (const float*)d_in[1];
    const float* th    = (const float*)d_in[2];
    const float* amb   = (const float*)d_in[3];
    float* out = (float*)d_out;

    // ws layout: Whi[32768 u16] | Wlo[32768 u16] | off[1024 f32] = 135,168 B
    unsigned short* Whi = (unsigned short*)d_ws;
    unsigned short* Wlo = Whi + MK * D_;
    float* offp = (float*)(Wlo + MK * D_);

    prep_kernel<<<MK / 256, 256, 0, stream>>>(alpha, th, amb, Whi, Wlo, offp);
    fern_mfma<<<NBLK, 512, 0, stream>>>(T, Whi, Wlo, offp, out);
}

// Round 17
// 168.507 us; speedup vs baseline: 1.0339x; 1.0339x over previous
//
#include <hip/hip_runtime.h>
#include <math.h>

// Problem constants (fixed by the reference)
#define N_TOT 200000
#define D_    32
#define MK    1024          // M*K = 64*16
#define EPS_DIV  1e-29f

// Decomposition: BLOCK = 16-row strip x 512-col half; 4 waves own 4 adjacent
// 128-col slices; cooperative row-linear store of the half-strip.
// FINAL (R17 = R11, empirical optimum 167.5us):
//   store contiguity curve: 64B:198 -> 512B:189.7 -> 1KB/instr+2KB rows:167.5
//   -> 4KB rows @2blk/CU: 174.2 (regressed). All other axes probed null/worse:
//   nt(+75), prefetch(+10), persistent(+8), pipeline(+30), relaxed-bar(0),
//   full-row(+7). 5.05 TB/s effective vs 6.7 TB/s same-buffer fill ceiling.
#define ROWS   16
#define HALF   512          // cols per block
#define NT     8            // 16-col MFMA tiles per wave (128 cols)
#define NSTRIP (N_TOT / ROWS)        // 12500
#define NTASK  (NSTRIP * 2)          // 25000 (strip, half) tasks
#define NBLK   4096         // even: task&1 == blockIdx&1 (half fixed per block)
#define LDSF   512          // stage row stride in f32 (no pad; XOR swizzle)

typedef __attribute__((ext_vector_type(8))) short short8;
typedef __attribute__((ext_vector_type(4))) float f32x4;

__device__ __forceinline__ unsigned short f2bf(float x) {
    unsigned int u = __float_as_uint(x);
    u += 0x7FFFu + ((u >> 16) & 1u);          // round-to-nearest-even
    return (unsigned short)(u >> 16);
}
__device__ __forceinline__ float bf2f(unsigned short h) {
    return __uint_as_float(((unsigned int)h) << 16);
}

// ---------------------------------------------------------------------------
// Prep: softmax(alpha) folded with affine epilogue, split into bf16 hi/lo.
//   W[mk][d] = softmax(alpha[mk])[d] / (pos-neg+eps)   -> Whi + Wlo (bf16)
//   off[mk]  = (-th-neg)/(pos-neg+eps)
// Then B = clip( T·W + off, 0, 1 ).  (|temp|<1e-5 zeroing folded away:
// <= ~5e-5 output delta, validated R7/R8/R10/R11 — absmax at 0.0039 floor.)
// ---------------------------------------------------------------------------
__global__ __launch_bounds__(256) void prep_kernel(
    const float* __restrict__ alpha, const float* __restrict__ th,
    const float* __restrict__ amb,
    unsigned short* __restrict__ Whi, unsigned short* __restrict__ Wlo,
    float* __restrict__ off)
{
    int mk = blockIdx.x * 256 + threadIdx.x;
    if (mk >= MK) return;
    float v[D_];
    float mx = -1e30f;
#pragma unroll
    for (int d = 0; d < D_; ++d) { v[d] = alpha[mk * D_ + d]; mx = fmaxf(mx, v[d]); }
    float sum = 0.f;
#pragma unroll
    for (int d = 0; d < D_; ++d) { v[d] = expf(v[d] - mx); sum += v[d]; }
    float pos = amb[mk * 2 + 0];
    float neg = amb[mk * 2 + 1];
    float s  = 1.0f / (pos - neg + EPS_DIV);
    float si = s / sum;
#pragma unroll
    for (int d = 0; d < D_; ++d) {
        float w = v[d] * si;
        unsigned short h = f2bf(w);
        Whi[mk * D_ + d] = h;
        Wlo[mk * D_ + d] = f2bf(w - bf2f(h));
    }
    off[mk] = (0.0f - th[mk] - neg) * s;
}

// ---------------------------------------------------------------------------
// Main: block-cooperative strip kernel with fully row-linear stores (R11).
// Compute phase (per wave, swapped operands — R8/R10-verified mapping):
//   acc f32x4 = 4 consecutive mk of one n-row -> one ds_write_b128 into the
//   block-shared stage [16 rows][512 f32], XOR-swizzled 16B chunks.
// Store phase (all 256 threads): 8 steps x {ds_read_b128, epilogue,
//   global_store_dwordx4}; each wave-instruction writes 1024 B CONTIGUOUS,
//   each row of the half-strip is one 2 KB run from one block.
// Half (col 0..511 vs 512..1023) is fixed per block (grid stride even), so W
// fragments + epilogue offsets stay register-hoisted.
// 3-MFMA hi/lo split keeps fp32-level accuracy (Tlo*Wlo term dropped).
// ---------------------------------------------------------------------------
__global__ __launch_bounds__(256, 4) void fern_mfma(
    const float* __restrict__ T,
    const unsigned short* __restrict__ Whi, const unsigned short* __restrict__ Wlo,
    const float* __restrict__ off, float* __restrict__ out)
{
    __shared__ float stage[ROWS][LDSF];         // 32 KB

    const int tid  = threadIdx.x;
    const int lane = tid & 63;
    const int wid  = tid >> 6;
    const int lc   = lane & 15;                 // A row (mk) / B col (n)
    const int lk   = lane >> 4;                 // k-group (8 contiguous k)
    const int half = blockIdx.x & 1;
    const int mkb  = half * HALF;
    const int mk0  = mkb + wid * 128;           // this wave's 128-col slice

    // ---- hoist W fragments (A operand, swapped) for this wave's 128 cols
    short8 wh[NT], wl[NT];
#pragma unroll
    for (int t = 0; t < NT; ++t) {
        long c = (long)(mk0 + t * 16 + lc);
        wh[t] = *(const short8*)(Whi + c * D_ + lk * 8);
        wl[t] = *(const short8*)(Wlo + c * D_ + lk * 8);
    }
    // ---- store-phase constants: thread covers cols mkb + 4*sc .. +3
    const int sc  = tid & 127;                  // 16B chunk within half-row
    const int sr0 = tid >> 7;                   // row parity (0/1)
    const f32x4 ofv = *(const f32x4*)(off + mkb + 4 * sc);

    // ---- grid-stride over (strip, half) tasks; task&1 == blockIdx&1 always
    for (int task = blockIdx.x; task < NTASK; task += NBLK) {
        const int n0 = (task >> 1) * ROWS;

        // T fragment (B operand): col n = n0+lc, k = lk*8 .. +7  (32 B of f32)
        const float* tp = T + (long)(n0 + lc) * D_ + lk * 8;
        float4 v0 = *(const float4*)tp;
        float4 v1 = *(const float4*)(tp + 4);
        float xs[8] = { v0.x, v0.y, v0.z, v0.w, v1.x, v1.y, v1.z, v1.w };
        short8 ah, al;
#pragma unroll
        for (int j = 0; j < 8; ++j) {
            unsigned short h = f2bf(xs[j]);
            ah[j] = (short)h;
            al[j] = (short)f2bf(xs[j] - bf2f(h));
        }

        // ---- compute 8 tiles; stage raw acc (1 ds_write_b128 per tile)
        // D[mk][n] swapped: n-row = lc, mk chunk = wid*32 + t*4 + lk
#pragma unroll
        for (int t = 0; t < NT; ++t) {
            f32x4 acc = { 0.f, 0.f, 0.f, 0.f };
            acc = __builtin_amdgcn_mfma_f32_16x16x32_bf16(wh[t], ah, acc, 0, 0, 0);
            acc = __builtin_amdgcn_mfma_f32_16x16x32_bf16(wh[t], al, acc, 0, 0, 0);
            acc = __builtin_amdgcn_mfma_f32_16x16x32_bf16(wl[t], ah, acc, 0, 0, 0);
            const int chunk = (wid * 32 + t * 4 + lk) ^ (lc & 7);   // XOR swizzle
            *(f32x4*)&stage[lc][chunk * 4] = acc;
        }
        __syncthreads();

        // ---- cooperative row-linear store: step s covers rows 2s, 2s+1;
        // each wave-instruction = 64 lanes x 16 B = 1024 B contiguous.
#pragma unroll
        for (int s = 0; s < 8; ++s) {
            const int r = 2 * s + sr0;
            const int k = sc ^ (r & 7);                              // un-swizzle
            f32x4 v = *(const f32x4*)&stage[r][k * 4];
            f32x4 rr;
#pragma unroll
            for (int j = 0; j < 4; ++j)
                rr[j] = fminf(fmaxf(v[j] + ofv[j], 0.f), 1.f);
            *(f32x4*)(out + (long)(n0 + r) * MK + mkb + 4 * sc) = rr;
        }
        __syncthreads();
    }
}

extern "C" void kernel_launch(void* const* d_in, const int* in_sizes, int n_in,
                              void* d_out, int out_size, void* d_ws, size_t ws_size,
                              hipStream_t stream)
{
    const float* T     = (const float*)d_in[0];
    const float* alpha = (const float*)d_in[1];
    const float* th    = (const float*)d_in[2];
    const float* amb   = (const float*)d_in[3];
    float* out = (float*)d_out;

    // ws layout: Whi[32768 u16] | Wlo[32768 u16] | off[1024 f32] = 135,168 B
    unsigned short* Whi = (unsigned short*)d_ws;
    unsigned short* Wlo = Whi + MK * D_;
    float* offp = (float*)(Wlo + MK * D_);

    prep_kernel<<<MK / 256, 256, 0, stream>>>(alpha, th, amb, Whi, Wlo, offp);
    fern_mfma<<<NBLK, 256, 0, stream>>>(T, Whi, Wlo, offp, out);
}